// Round 8
// baseline (767.576 us; speedup 1.0000x reference)
//
#include <hip/hip_runtime.h>

#define N_ATOMS 200000
#define N_EDGES 800000
#define FDIM    133
#define HID     256
#define NMOLS   8000
#define CAP     32   // Poisson(4) in-degree; P(deg>=32) ~ 1e-20

typedef unsigned short bf16_t;
typedef __attribute__((ext_vector_type(4))) float f32x4;
typedef __attribute__((ext_vector_type(8))) short bf16x8;

__device__ inline float bf2f(bf16_t u) {
    union { unsigned int i; float f; } v; v.i = ((unsigned int)u) << 16; return v.f;
}
__device__ inline bf16_t f2bf(float f) {
    union { float f; unsigned int i; } v; v.f = f;
    return (bf16_t)((v.i + 0x7fffu + ((v.i >> 16) & 1u)) >> 16);   // RNE
}
__device__ inline float4 ld4(const bf16_t* p) {
    ushort4 u = *(const ushort4*)p;
    return make_float4(bf2f(u.x), bf2f(u.y), bf2f(u.z), bf2f(u.w));
}
__device__ inline void st4(bf16_t* p, float4 v) {
    ushort4 u; u.x = f2bf(v.x); u.y = f2bf(v.y); u.z = f2bf(v.z); u.w = f2bf(v.w);
    *(ushort4*)p = u;
}

// ---------------- adjacency build (edge_index arrives as int32) ----------------
__global__ __launch_bounds__(256) void build_adj(const int* __restrict__ ei,
                                                 int* __restrict__ cnt,
                                                 int* __restrict__ lst) {
    int e = blockIdx.x * 256 + threadIdx.x;
    if (e >= N_EDGES) return;
    int s = ei[e];
    int t = ei[N_EDGES + e];
    int p = atomicAdd(&cnt[t], 1);
    if (p < CAP) lst[t * CAP + p] = s;
}

// ---------------- weight transpose+convert: Wt[n][k] = bf16(W[k][n]), zero-pad k>=K ----------------
__global__ __launch_bounds__(256) void transpose_w(const float* __restrict__ W,
                                                   bf16_t* __restrict__ Wt,
                                                   int K, int Kpad) {
    int idx = blockIdx.x * 256 + threadIdx.x;
    if (idx >= HID * Kpad) return;
    int n = idx / Kpad, k = idx - n * Kpad;
    Wt[idx] = (k < K) ? f2bf(W[k * HID + n]) : (bf16_t)0;
}

// ---------------- barrier-free direct-register MFMA GEMM + fused dot partials ----------------
// H[M x 256] = A[M x K] @ W  (Wt[256][KP] = W^T in bf16, zero-padded K).
// One block = 64 rows x 256 cols: 4 waves, wave w owns cols w*64..w*64+63 and
// shares the same 64 A-rows (L1 reuse). MFMA fragments are loaded DIRECTLY
// from global memory (16B/lane, aligned): no LDS, no __syncthreads, no convoy.
// M = 3125*64 exactly -> no row guards anywhere.
// Epilogue: bf16 H store + per-row dot partials (this wave's 64 cols) into
// slot w -- unique writer per (slot, row), no races.
template <bool A_FP32, int KSTEPS, int LDA, int KP>
__global__ __launch_bounds__(256) void gemm_direct(const void* __restrict__ Av,
                                                   const bf16_t* __restrict__ Wt,
                                                   bf16_t* __restrict__ H,
                                                   const float* __restrict__ avec,
                                                   float* __restrict__ ssp,
                                                   float* __restrict__ stp) {
    const int tid  = threadIdx.x;
    const int lane = tid & 63;
    const int w    = tid >> 6;       // col-group 0..3
    const int fr   = lane & 15;      // fragment row/col lane
    const int kg   = lane >> 4;      // k-group 0..3
    const int row0 = blockIdx.x * 64;
    const int col0 = w * 64;

    ssp += (long long)w * N_ATOMS;
    stp += (long long)w * N_ATOMS;

    f32x4 acc[4][4] = {};

    #pragma unroll 2
    for (int ks = 0; ks < KSTEPS; ++ks) {
        const int kbase = ks * 32 + kg * 8;
        bf16x8 af[4], bfr[4];

        if constexpr (A_FP32) {
            const float* A = (const float*)Av;
            #pragma unroll
            for (int i = 0; i < 4; ++i) {
                const float* src = A + (long long)(row0 + i * 16 + fr) * LDA + kbase;
                short v[8];
                #pragma unroll
                for (int j = 0; j < 8; ++j)
                    v[j] = (kbase + j < LDA) ? (short)f2bf(src[j]) : (short)0;
                af[i] = *(bf16x8*)v;
            }
        } else {
            const bf16_t* A = (const bf16_t*)Av;
            #pragma unroll
            for (int i = 0; i < 4; ++i)
                af[i] = *(const bf16x8*)(A + (long long)(row0 + i * 16 + fr) * LDA + kbase);
        }
        #pragma unroll
        for (int jn = 0; jn < 4; ++jn)
            bfr[jn] = *(const bf16x8*)(Wt + (long long)(col0 + jn * 16 + fr) * KP + kbase);

        #pragma unroll
        for (int i = 0; i < 4; ++i)
            #pragma unroll
            for (int jn = 0; jn < 4; ++jn)
                acc[i][jn] = __builtin_amdgcn_mfma_f32_16x16x32_bf16(af[i], bfr[jn], acc[i][jn], 0, 0, 0);
    }

    // ---- epilogue: H store (bf16) + fused dot partials from fp32 acc ----
    float as_v[4], at_v[4];
    #pragma unroll
    for (int jn = 0; jn < 4; ++jn) {
        int c = col0 + jn * 16 + fr;
        as_v[jn] = avec[c];
        at_v[jn] = avec[HID + c];
    }
    #pragma unroll
    for (int i = 0; i < 4; ++i) {
        #pragma unroll
        for (int rr = 0; rr < 4; ++rr) {
            int r = row0 + i * 16 + kg * 4 + rr;   // always < N_ATOMS (M = 3125*64)
            float ps = 0.f, pt = 0.f;
            #pragma unroll
            for (int jn = 0; jn < 4; ++jn) {
                float h = acc[i][jn][rr];
                ps += h * as_v[jn];
                pt += h * at_v[jn];
                H[(long long)r * HID + (col0 + jn * 16 + fr)] = f2bf(h);
            }
            #pragma unroll
            for (int o = 1; o < 16; o <<= 1) {     // reduce across the 16 col-lanes
                ps += __shfl_xor(ps, o);
                pt += __shfl_xor(pt, o);
            }
            if (fr == 0) {
                ssp[r] = ps;                        // unique writer: slot w, row r
                stp[r] = pt;
            }
        }
    }
}

// ---------------- combine the 4 per-slot dot partials ----------------
__global__ __launch_bounds__(256) void combine_dots(const float* __restrict__ ssp,
                                                    const float* __restrict__ stp,
                                                    float* __restrict__ ss,
                                                    float* __restrict__ st) {
    int i = blockIdx.x * 256 + threadIdx.x;
    if (i >= N_ATOMS) return;
    ss[i] = (ssp[i] + ssp[N_ATOMS + i]) + (ssp[2 * N_ATOMS + i] + ssp[3 * N_ATOMS + i]);
    st[i] = (stp[i] + stp[N_ATOMS + i]) + (stp[2 * N_ATOMS + i] + stp[3 * N_ATOMS + i]);
}

// ---------------- fused softmax-aggregate + residual + ELU ----------------
// One wave per target; edges in chunks of 4 -> 4 independent gathers in flight.
__global__ __launch_bounds__(256) void aggregate(const bf16_t* __restrict__ H,
                                                 const float* __restrict__ ss,
                                                 const float* __restrict__ st,
                                                 const int* __restrict__ cnt,
                                                 const int* __restrict__ lst,
                                                 bf16_t* __restrict__ X,
                                                 int residual) {
    int wave = threadIdx.x >> 6;
    int lane = threadIdx.x & 63;
    int t = blockIdx.x * 4 + wave;
    if (t >= N_ATOMS) return;
    int n = cnt[t]; if (n > CAP) n = CAP;
    float stt = st[t];
    const int base = t * CAP;

    float ax = 0.f, ay = 0.f, az = 0.f, aw = 0.f;
    float denom = 0.f;

    for (int i0 = 0; i0 < n; i0 += 4) {
        int4 s4 = *(const int4*)&lst[base + i0];
        int s0 = (i0 + 0 < n) ? s4.x : t;
        int s1 = (i0 + 1 < n) ? s4.y : t;
        int s2 = (i0 + 2 < n) ? s4.z : t;
        int s3 = (i0 + 3 < n) ? s4.w : t;

        float v0 = ss[s0], v1 = ss[s1], v2 = ss[s2], v3 = ss[s3];

        float e0 = v0 + stt; e0 = e0 > 0.f ? e0 : 0.2f * e0;
        float e1 = v1 + stt; e1 = e1 > 0.f ? e1 : 0.2f * e1;
        float e2 = v2 + stt; e2 = e2 > 0.f ? e2 : 0.2f * e2;
        float e3 = v3 + stt; e3 = e3 > 0.f ? e3 : 0.2f * e3;

        float t0 = (i0 + 0 < n) ? __expf(e0) : 0.f;
        float t1 = (i0 + 1 < n) ? __expf(e1) : 0.f;
        float t2 = (i0 + 2 < n) ? __expf(e2) : 0.f;
        float t3 = (i0 + 3 < n) ? __expf(e3) : 0.f;

        float4 h0 = ld4(&H[(long long)s0 * HID + lane * 4]);
        float4 h1 = ld4(&H[(long long)s1 * HID + lane * 4]);
        float4 h2 = ld4(&H[(long long)s2 * HID + lane * 4]);
        float4 h3 = ld4(&H[(long long)s3 * HID + lane * 4]);

        denom += (t0 + t1) + (t2 + t3);
        ax += t0 * h0.x + t1 * h1.x + t2 * h2.x + t3 * h3.x;
        ay += t0 * h0.y + t1 * h1.y + t2 * h2.y + t3 * h3.y;
        az += t0 * h0.z + t1 * h1.z + t2 * h2.z + t3 * h3.z;
        aw += t0 * h0.w + t1 * h1.w + t2 * h2.w + t3 * h3.w;
    }

    float inv = 1.f / (denom + 1e-8f);
    float rx = ax * inv, ry = ay * inv, rz = az * inv, rw = aw * inv;
    if (residual) {
        float4 xv = ld4(&X[(long long)t * HID + lane * 4]);
        rx += xv.x; ry += xv.y; rz += xv.z; rw += xv.w;
    }
    rx = rx > 0.f ? rx : (__expf(rx) - 1.f);   // elu(alpha=1)
    ry = ry > 0.f ? ry : (__expf(ry) - 1.f);
    rz = rz > 0.f ? rz : (__expf(rz) - 1.f);
    rw = rw > 0.f ? rw : (__expf(rw) - 1.f);
    st4(&X[(long long)t * HID + lane * 4], make_float4(rx, ry, rz, rw));
}

// ---------------- molecule mean pool (mol_ids int32, sorted) ----------------
__device__ inline int lower_bound_i(const int* a, int n, int v) {
    int lo = 0, hi = n;
    while (lo < hi) { int mid = (lo + hi) >> 1; if (a[mid] < v) lo = mid + 1; else hi = mid; }
    return lo;
}

__global__ __launch_bounds__(64) void pool_kernel(const bf16_t* __restrict__ X,
                                                  const int* __restrict__ mol,
                                                  float* __restrict__ out) {
    int m = blockIdx.x;
    int lane = threadIdx.x;
    int lo = lower_bound_i(mol, N_ATOMS, m);
    int hi = lower_bound_i(mol, N_ATOMS, m + 1);
    float ax = 0.f, ay = 0.f, az = 0.f, aw = 0.f;
    for (int i = lo; i < hi; ++i) {
        float4 v = ld4(&X[(long long)i * HID + lane * 4]);
        ax += v.x; ay += v.y; az += v.z; aw += v.w;
    }
    float c = (float)(hi - lo);
    float4 r = make_float4(0.f, 0.f, 0.f, 0.f);
    if (c > 0.f) {
        float inv = 1.f / c;
        r = make_float4(ax * inv, ay * inv, az * inv, aw * inv);
    }
    *(float4*)&out[(long long)m * HID + lane * 4] = r;
}

extern "C" void kernel_launch(void* const* d_in, const int* in_sizes, int n_in,
                              void* d_out, int out_size, void* d_ws, size_t ws_size,
                              hipStream_t stream) {
    const float* f_atoms = (const float*)d_in[0];
    const int*   ei      = (const int*)d_in[1];
    const int*   mol     = (const int*)d_in[2];
    const float* W0      = (const float*)d_in[3];
    const float* a0      = (const float*)d_in[4];
    const float* W1      = (const float*)d_in[5];
    const float* a1      = (const float*)d_in[6];
    const float* W2      = (const float*)d_in[7];
    const float* a2      = (const float*)d_in[8];
    float* out = (float*)d_out;

    char* ws = (char*)d_ws;
    size_t off = 0;
    bf16_t* X  = (bf16_t*)(ws + off); off += (size_t)N_ATOMS * HID * 2;   // 102.4 MB
    bf16_t* Hb = (bf16_t*)(ws + off); off += (size_t)N_ATOMS * HID * 2;   // 102.4 MB
    float* ss  = (float*)(ws + off);  off += (size_t)N_ATOMS * 4;
    float* st  = (float*)(ws + off);  off += (size_t)N_ATOMS * 4;
    int* cnt   = (int*)(ws + off);    off += (size_t)N_ATOMS * 4;
    int* lst   = (int*)(ws + off);    off += (size_t)N_ATOMS * CAP * 4;   // 25.6 MB
    if (ws_size < off) return;

    // scratch carved from d_out (8.19 MB): Wt 131KB + 4-slot ssp/stp (3.2MB each).
    // pool_kernel overwrites ALL of d_out at the end.
    char* ob = (char*)d_out;
    bf16_t* Wt  = (bf16_t*)ob;                          // 131072 B
    float*  ssp = (float*)(ob + 131072);                // 4 x N_ATOMS f32 = 3.2 MB
    float*  stp = (float*)(ob + 131072 + 3200000);      // 4 x N_ATOMS f32 = 3.2 MB

    hipMemsetAsync(cnt, 0, (size_t)N_ATOMS * 4, stream);
    build_adj<<<(N_EDGES + 255) / 256, 256, 0, stream>>>(ei, cnt, lst);

    const int gemm_blocks = N_ATOMS / 64;   // 3125, exact
    const int agg_blocks  = N_ATOMS / 4;
    const int cmb_blocks  = (N_ATOMS + 255) / 256;

    // ---- layer 0: A = f_atoms fp32, K=133 padded to 160 ----
    transpose_w<<<(HID * 160 + 255) / 256, 256, 0, stream>>>(W0, Wt, FDIM, 160);
    gemm_direct<true, 5, FDIM, 160><<<gemm_blocks, 256, 0, stream>>>(f_atoms, Wt, Hb, a0, ssp, stp);
    combine_dots<<<cmb_blocks, 256, 0, stream>>>(ssp, stp, ss, st);
    aggregate<<<agg_blocks, 256, 0, stream>>>(Hb, ss, st, cnt, lst, X, 0);

    // ---- layer 1 ----
    transpose_w<<<(HID * HID + 255) / 256, 256, 0, stream>>>(W1, Wt, HID, HID);
    gemm_direct<false, 8, HID, HID><<<gemm_blocks, 256, 0, stream>>>(X, Wt, Hb, a1, ssp, stp);
    combine_dots<<<cmb_blocks, 256, 0, stream>>>(ssp, stp, ss, st);
    aggregate<<<agg_blocks, 256, 0, stream>>>(Hb, ss, st, cnt, lst, X, 1);

    // ---- layer 2 ----
    transpose_w<<<(HID * HID + 255) / 256, 256, 0, stream>>>(W2, Wt, HID, HID);
    gemm_direct<false, 8, HID, HID><<<gemm_blocks, 256, 0, stream>>>(X, Wt, Hb, a2, ssp, stp);
    combine_dots<<<cmb_blocks, 256, 0, stream>>>(ssp, stp, ss, st);
    aggregate<<<agg_blocks, 256, 0, stream>>>(Hb, ss, st, cnt, lst, X, 1);

    pool_kernel<<<NMOLS, 64, 0, stream>>>(X, mol, out);
}

// Round 9
// 602.424 us; speedup vs baseline: 1.2741x; 1.2741x over previous
//
#include <hip/hip_runtime.h>

#define N_ATOMS 200000
#define N_EDGES 800000
#define FDIM    133
#define HID     256
#define NMOLS   8000
#define CAP     32   // Poisson(4) in-degree; P(deg>=32) ~ 1e-20

typedef unsigned short bf16_t;
typedef __attribute__((ext_vector_type(4))) float f32x4;
typedef __attribute__((ext_vector_type(8))) short bf16x8;

__device__ inline float bf2f(bf16_t u) {
    union { unsigned int i; float f; } v; v.i = ((unsigned int)u) << 16; return v.f;
}
__device__ inline bf16_t f2bf(float f) {
    union { float f; unsigned int i; } v; v.f = f;
    return (bf16_t)((v.i + 0x7fffu + ((v.i >> 16) & 1u)) >> 16);   // RNE
}
__device__ inline float4 ld4(const bf16_t* p) {
    ushort4 u = *(const ushort4*)p;
    return make_float4(bf2f(u.x), bf2f(u.y), bf2f(u.z), bf2f(u.w));
}
__device__ inline void st4(bf16_t* p, float4 v) {
    ushort4 u; u.x = f2bf(v.x); u.y = f2bf(v.y); u.z = f2bf(v.z); u.w = f2bf(v.w);
    *(ushort4*)p = u;
}

// async global->LDS, 16B/lane; lds dest is wave-uniform base (+lane*16 implicit)
__device__ inline void gload_lds16(const void* g, void* l) {
    __builtin_amdgcn_global_load_lds((const __attribute__((address_space(1))) unsigned int*)g,
                                     (__attribute__((address_space(3))) unsigned int*)l,
                                     16, 0, 0);
}

// ---------------- adjacency build (edge_index arrives as int32) ----------------
__global__ __launch_bounds__(256) void build_adj(const int* __restrict__ ei,
                                                 int* __restrict__ cnt,
                                                 int* __restrict__ lst) {
    int e = blockIdx.x * 256 + threadIdx.x;
    if (e >= N_EDGES) return;
    int s = ei[e];
    int t = ei[N_EDGES + e];
    int p = atomicAdd(&cnt[t], 1);
    if (p < CAP) lst[t * CAP + p] = s;
}

// ---------------- weight transpose+convert: Wt[n][k] = bf16(W[k][n]), zero-pad k>=K ----------------
__global__ __launch_bounds__(256) void transpose_w(const float* __restrict__ W,
                                                   bf16_t* __restrict__ Wt,
                                                   int K, int Kpad) {
    int idx = blockIdx.x * 256 + threadIdx.x;
    if (idx >= HID * Kpad) return;
    int n = idx / Kpad, k = idx - n * Kpad;
    Wt[idx] = (k < K) ? f2bf(W[k * HID + n]) : (bf16_t)0;
}

// ---------------- 8-wave full-N MFMA GEMM + fused dot partials ----------------
// H[M x 256] = A[M x K] @ W (Wt[256][KP] = W^T bf16, K zero-padded).
// Block = 128 rows x 256 cols, 8 waves (2 row-groups x 4 col-groups).
// A staged ONCE per 128 rows (full N in one block); Bs holds all 256 cols.
// Single-buffer LDS (24KB), 2 barriers/K-step (round-5 structure, widened).
// Epilogue: bf16 H store + per-row dot partials into slot wc (unique writer).
template <bool A_FP32, int KSTEPS, int LDA, int KP>
__global__ __launch_bounds__(512, 4) void gemm_mfma(const void* __restrict__ Av,
                                                    const bf16_t* __restrict__ Wt,
                                                    bf16_t* __restrict__ H,
                                                    const float* __restrict__ avec,
                                                    float* __restrict__ ssp,
                                                    float* __restrict__ stp) {
    __shared__ bf16_t As[128][32];   // 8 KB
    __shared__ bf16_t Bs[256][32];   // 16 KB
    const int tid  = threadIdx.x;
    const int lane = tid & 63;
    const int w    = tid >> 6;       // wave 0..7
    const int wr   = w >> 2;         // row-group 0..1  (64 rows each)
    const int wc   = w & 3;          // col-group 0..3  (64 cols each)
    const int fr   = lane & 15;
    const int kg   = lane >> 4;      // k-group 0..3
    const int row0 = blockIdx.x * 128;

    // staging coordinates (byte u = tid*16 within As; Bs gets 2 chunks)
    const int sra  = tid >> 2;              // As row 0..127
    const int ska  = (tid & 3) * 8;         // As elem offset
    int sgrow = row0 + sra; if (sgrow >= N_ATOMS) sgrow = N_ATOMS - 1;

    ssp += (long long)wc * N_ATOMS;
    stp += (long long)wc * N_ATOMS;

    f32x4 acc[4][4] = {};

    for (int ks = 0; ks < KSTEPS; ++ks) {
        const int k0 = ks * 32;
        if (ks) __syncthreads();            // previous compute done before overwrite

        // ---- stage A tile (128 x 32 bf16 = 8KB; 512 lanes x 16B, one op each) ----
        if constexpr (A_FP32) {
            const float* A = (const float*)Av;
            short v[8];
            #pragma unroll
            for (int j = 0; j < 8; ++j) {
                int gk = k0 + ska + j;
                v[j] = (gk < LDA) ? (short)f2bf(A[(long long)sgrow * LDA + gk]) : (short)0;
            }
            *(bf16x8*)&As[sra][ska] = *(bf16x8*)v;
        } else {
            gload_lds16((const bf16_t*)Av + (long long)sgrow * LDA + k0 + ska,
                        (char*)&As[0][0] + w * 1024);
        }
        // ---- stage B tile (256 x 32 bf16 = 16KB; 2 x 16B per lane) ----
        gload_lds16(Wt + (long long)(tid >> 2) * KP + k0 + ska,
                    (char*)&Bs[0][0] + w * 1024);
        gload_lds16(Wt + (long long)(128 + (tid >> 2)) * KP + k0 + ska,
                    (char*)&Bs[0][0] + 8192 + w * 1024);
        __syncthreads();                    // staging drained (vmcnt+lgkm) before reads

        // ---- fragments + MFMA ----
        const int koff = kg * 8;
        bf16x8 af[4], bfr[4];
        #pragma unroll
        for (int i = 0; i < 4; ++i)
            af[i] = *(const bf16x8*)&As[wr * 64 + i * 16 + fr][koff];
        #pragma unroll
        for (int jn = 0; jn < 4; ++jn)
            bfr[jn] = *(const bf16x8*)&Bs[wc * 64 + jn * 16 + fr][koff];
        #pragma unroll
        for (int i = 0; i < 4; ++i)
            #pragma unroll
            for (int jn = 0; jn < 4; ++jn)
                acc[i][jn] = __builtin_amdgcn_mfma_f32_16x16x32_bf16(af[i], bfr[jn], acc[i][jn], 0, 0, 0);
    }

    // ---- epilogue: H store (bf16) + fused dot partials from fp32 acc ----
    float as_v[4], at_v[4];
    #pragma unroll
    for (int jn = 0; jn < 4; ++jn) {
        int c = wc * 64 + jn * 16 + fr;
        as_v[jn] = avec[c];
        at_v[jn] = avec[HID + c];
    }
    #pragma unroll
    for (int i = 0; i < 4; ++i) {
        #pragma unroll
        for (int rr = 0; rr < 4; ++rr) {
            int r = row0 + wr * 64 + i * 16 + kg * 4 + rr;
            float ps = 0.f, pt = 0.f;
            #pragma unroll
            for (int jn = 0; jn < 4; ++jn) {
                float h = acc[i][jn][rr];
                ps += h * as_v[jn];
                pt += h * at_v[jn];
                if (r < N_ATOMS)
                    H[(long long)r * HID + (wc * 64 + jn * 16 + fr)] = f2bf(h);
            }
            #pragma unroll
            for (int o = 1; o < 16; o <<= 1) {   // reduce across the 16 col-lanes
                ps += __shfl_xor(ps, o);
                pt += __shfl_xor(pt, o);
            }
            if (fr == 0 && r < N_ATOMS) {
                ssp[r] = ps;                      // unique writer: slot wc, row r
                stp[r] = pt;
            }
        }
    }
}

// ---------------- combine the 4 per-slot dot partials ----------------
__global__ __launch_bounds__(256) void combine_dots(const float* __restrict__ ssp,
                                                    const float* __restrict__ stp,
                                                    float* __restrict__ ss,
                                                    float* __restrict__ st) {
    int i = blockIdx.x * 256 + threadIdx.x;
    if (i >= N_ATOMS) return;
    ss[i] = (ssp[i] + ssp[N_ATOMS + i]) + (ssp[2 * N_ATOMS + i] + ssp[3 * N_ATOMS + i]);
    st[i] = (stp[i] + stp[N_ATOMS + i]) + (stp[2 * N_ATOMS + i] + stp[3 * N_ATOMS + i]);
}

// ---------------- fused softmax-aggregate + residual + ELU ----------------
// One wave per target; edges in chunks of 4 -> 4 independent gathers in flight.
__global__ __launch_bounds__(256) void aggregate(const bf16_t* __restrict__ H,
                                                 const float* __restrict__ ss,
                                                 const float* __restrict__ st,
                                                 const int* __restrict__ cnt,
                                                 const int* __restrict__ lst,
                                                 bf16_t* __restrict__ X,
                                                 int residual) {
    int wave = threadIdx.x >> 6;
    int lane = threadIdx.x & 63;
    int t = blockIdx.x * 4 + wave;
    if (t >= N_ATOMS) return;
    int n = cnt[t]; if (n > CAP) n = CAP;
    float stt = st[t];
    const int base = t * CAP;

    float ax = 0.f, ay = 0.f, az = 0.f, aw = 0.f;
    float denom = 0.f;

    for (int i0 = 0; i0 < n; i0 += 4) {
        int4 s4 = *(const int4*)&lst[base + i0];
        int s0 = (i0 + 0 < n) ? s4.x : t;
        int s1 = (i0 + 1 < n) ? s4.y : t;
        int s2 = (i0 + 2 < n) ? s4.z : t;
        int s3 = (i0 + 3 < n) ? s4.w : t;

        float v0 = ss[s0], v1 = ss[s1], v2 = ss[s2], v3 = ss[s3];

        float e0 = v0 + stt; e0 = e0 > 0.f ? e0 : 0.2f * e0;
        float e1 = v1 + stt; e1 = e1 > 0.f ? e1 : 0.2f * e1;
        float e2 = v2 + stt; e2 = e2 > 0.f ? e2 : 0.2f * e2;
        float e3 = v3 + stt; e3 = e3 > 0.f ? e3 : 0.2f * e3;

        float t0 = (i0 + 0 < n) ? __expf(e0) : 0.f;
        float t1 = (i0 + 1 < n) ? __expf(e1) : 0.f;
        float t2 = (i0 + 2 < n) ? __expf(e2) : 0.f;
        float t3 = (i0 + 3 < n) ? __expf(e3) : 0.f;

        float4 h0 = ld4(&H[(long long)s0 * HID + lane * 4]);
        float4 h1 = ld4(&H[(long long)s1 * HID + lane * 4]);
        float4 h2 = ld4(&H[(long long)s2 * HID + lane * 4]);
        float4 h3 = ld4(&H[(long long)s3 * HID + lane * 4]);

        denom += (t0 + t1) + (t2 + t3);
        ax += t0 * h0.x + t1 * h1.x + t2 * h2.x + t3 * h3.x;
        ay += t0 * h0.y + t1 * h1.y + t2 * h2.y + t3 * h3.y;
        az += t0 * h0.z + t1 * h1.z + t2 * h2.z + t3 * h3.z;
        aw += t0 * h0.w + t1 * h1.w + t2 * h2.w + t3 * h3.w;
    }

    float inv = 1.f / (denom + 1e-8f);
    float rx = ax * inv, ry = ay * inv, rz = az * inv, rw = aw * inv;
    if (residual) {
        float4 xv = ld4(&X[(long long)t * HID + lane * 4]);
        rx += xv.x; ry += xv.y; rz += xv.z; rw += xv.w;
    }
    rx = rx > 0.f ? rx : (__expf(rx) - 1.f);   // elu(alpha=1)
    ry = ry > 0.f ? ry : (__expf(ry) - 1.f);
    rz = rz > 0.f ? rz : (__expf(rz) - 1.f);
    rw = rw > 0.f ? rw : (__expf(rw) - 1.f);
    st4(&X[(long long)t * HID + lane * 4], make_float4(rx, ry, rz, rw));
}

// ---------------- molecule mean pool (mol_ids int32, sorted) ----------------
__device__ inline int lower_bound_i(const int* a, int n, int v) {
    int lo = 0, hi = n;
    while (lo < hi) { int mid = (lo + hi) >> 1; if (a[mid] < v) lo = mid + 1; else hi = mid; }
    return lo;
}

__global__ __launch_bounds__(64) void pool_kernel(const bf16_t* __restrict__ X,
                                                  const int* __restrict__ mol,
                                                  float* __restrict__ out) {
    int m = blockIdx.x;
    int lane = threadIdx.x;
    int lo = lower_bound_i(mol, N_ATOMS, m);
    int hi = lower_bound_i(mol, N_ATOMS, m + 1);
    float ax = 0.f, ay = 0.f, az = 0.f, aw = 0.f;
    for (int i = lo; i < hi; ++i) {
        float4 v = ld4(&X[(long long)i * HID + lane * 4]);
        ax += v.x; ay += v.y; az += v.z; aw += v.w;
    }
    float c = (float)(hi - lo);
    float4 r = make_float4(0.f, 0.f, 0.f, 0.f);
    if (c > 0.f) {
        float inv = 1.f / c;
        r = make_float4(ax * inv, ay * inv, az * inv, aw * inv);
    }
    *(float4*)&out[(long long)m * HID + lane * 4] = r;
}

extern "C" void kernel_launch(void* const* d_in, const int* in_sizes, int n_in,
                              void* d_out, int out_size, void* d_ws, size_t ws_size,
                              hipStream_t stream) {
    const float* f_atoms = (const float*)d_in[0];
    const int*   ei      = (const int*)d_in[1];
    const int*   mol     = (const int*)d_in[2];
    const float* W0      = (const float*)d_in[3];
    const float* a0      = (const float*)d_in[4];
    const float* W1      = (const float*)d_in[5];
    const float* a1      = (const float*)d_in[6];
    const float* W2      = (const float*)d_in[7];
    const float* a2      = (const float*)d_in[8];
    float* out = (float*)d_out;

    char* ws = (char*)d_ws;
    size_t off = 0;
    bf16_t* X  = (bf16_t*)(ws + off); off += (size_t)N_ATOMS * HID * 2;   // 102.4 MB
    bf16_t* Hb = (bf16_t*)(ws + off); off += (size_t)N_ATOMS * HID * 2;   // 102.4 MB
    float* ss  = (float*)(ws + off);  off += (size_t)N_ATOMS * 4;
    float* st  = (float*)(ws + off);  off += (size_t)N_ATOMS * 4;
    int* cnt   = (int*)(ws + off);    off += (size_t)N_ATOMS * 4;
    int* lst   = (int*)(ws + off);    off += (size_t)N_ATOMS * CAP * 4;   // 25.6 MB
    if (ws_size < off) return;

    // scratch carved from d_out (8.19 MB): Wt 131KB + 4-slot ssp/stp (3.2MB each).
    // pool_kernel overwrites ALL of d_out at the end.
    char* ob = (char*)d_out;
    bf16_t* Wt  = (bf16_t*)ob;                          // 131072 B
    float*  ssp = (float*)(ob + 131072);                // 4 x N_ATOMS f32 = 3.2 MB
    float*  stp = (float*)(ob + 131072 + 3200000);      // 4 x N_ATOMS f32 = 3.2 MB

    hipMemsetAsync(cnt, 0, (size_t)N_ATOMS * 4, stream);
    build_adj<<<(N_EDGES + 255) / 256, 256, 0, stream>>>(ei, cnt, lst);

    const int gemm_blocks = (N_ATOMS + 127) / 128;   // 1563
    const int agg_blocks  = N_ATOMS / 4;
    const int cmb_blocks  = (N_ATOMS + 255) / 256;

    // ---- layer 0: A = f_atoms fp32, K=133 padded to 160 ----
    transpose_w<<<(HID * 160 + 255) / 256, 256, 0, stream>>>(W0, Wt, FDIM, 160);
    gemm_mfma<true, 5, FDIM, 160><<<gemm_blocks, 512, 0, stream>>>(f_atoms, Wt, Hb, a0, ssp, stp);
    combine_dots<<<cmb_blocks, 256, 0, stream>>>(ssp, stp, ss, st);
    aggregate<<<agg_blocks, 256, 0, stream>>>(Hb, ss, st, cnt, lst, X, 0);

    // ---- layer 1 ----
    transpose_w<<<(HID * HID + 255) / 256, 256, 0, stream>>>(W1, Wt, HID, HID);
    gemm_mfma<false, 8, HID, HID><<<gemm_blocks, 512, 0, stream>>>(X, Wt, Hb, a1, ssp, stp);
    combine_dots<<<cmb_blocks, 256, 0, stream>>>(ssp, stp, ss, st);
    aggregate<<<agg_blocks, 256, 0, stream>>>(Hb, ss, st, cnt, lst, X, 1);

    // ---- layer 2 ----
    transpose_w<<<(HID * HID + 255) / 256, 256, 0, stream>>>(W2, Wt, HID, HID);
    gemm_mfma<false, 8, HID, HID><<<gemm_blocks, 512, 0, stream>>>(X, Wt, Hb, a2, ssp, stp);
    combine_dots<<<cmb_blocks, 256, 0, stream>>>(ssp, stp, ss, st);
    aggregate<<<agg_blocks, 256, 0, stream>>>(Hb, ss, st, cnt, lst, X, 1);

    pool_kernel<<<NMOLS, 64, 0, stream>>>(X, mol, out);
}

// Round 10
// 601.565 us; speedup vs baseline: 1.2760x; 1.0014x over previous
//
#include <hip/hip_runtime.h>

#define N_ATOMS 200000
#define N_EDGES 800000
#define FDIM    133
#define HID     256
#define NMOLS   8000
#define CAP     32        // Poisson(4) in-degree; P(deg>=32) ~ 1e-20
#define AGG_BLOCKS 2048   // 8192 persistent waves

typedef unsigned short bf16_t;
typedef __attribute__((ext_vector_type(4))) float f32x4;
typedef __attribute__((ext_vector_type(8))) short bf16x8;

__device__ inline float bf2f(bf16_t u) {
    union { unsigned int i; float f; } v; v.i = ((unsigned int)u) << 16; return v.f;
}
__device__ inline bf16_t f2bf(float f) {
    union { float f; unsigned int i; } v; v.f = f;
    return (bf16_t)((v.i + 0x7fffu + ((v.i >> 16) & 1u)) >> 16);   // RNE
}
__device__ inline float4 ld4(const bf16_t* p) {
    ushort4 u = *(const ushort4*)p;
    return make_float4(bf2f(u.x), bf2f(u.y), bf2f(u.z), bf2f(u.w));
}
__device__ inline void st4(bf16_t* p, float4 v) {
    ushort4 u; u.x = f2bf(v.x); u.y = f2bf(v.y); u.z = f2bf(v.z); u.w = f2bf(v.w);
    *(ushort4*)p = u;
}

// async global->LDS, 16B/lane; lds dest is wave-uniform base (+lane*16 implicit)
__device__ inline void gload_lds16(const void* g, void* l) {
    __builtin_amdgcn_global_load_lds((const __attribute__((address_space(1))) unsigned int*)g,
                                     (__attribute__((address_space(3))) unsigned int*)l,
                                     16, 0, 0);
}

// ---------------- adjacency build (edge_index arrives as int32) ----------------
__global__ __launch_bounds__(256) void build_adj(const int* __restrict__ ei,
                                                 int* __restrict__ cnt,
                                                 int* __restrict__ lst) {
    int e = blockIdx.x * 256 + threadIdx.x;
    if (e >= N_EDGES) return;
    int s = ei[e];
    int t = ei[N_EDGES + e];
    int p = atomicAdd(&cnt[t], 1);
    if (p < CAP) lst[t * CAP + p] = s;
}

// ---------------- weight transpose+convert: Wt[n][k] = bf16(W[k][n]), zero-pad k>=K ----------------
__global__ __launch_bounds__(256) void transpose_w(const float* __restrict__ W,
                                                   bf16_t* __restrict__ Wt,
                                                   int K, int Kpad) {
    int idx = blockIdx.x * 256 + threadIdx.x;
    if (idx >= HID * Kpad) return;
    int n = idx / Kpad, k = idx - n * Kpad;
    Wt[idx] = (k < K) ? f2bf(W[k * HID + n]) : (bf16_t)0;
}

// ---------------- 8-wave full-N MFMA GEMM + fused dots (final ss/st via LDS reduce) ----
// H[M x 256] = A[M x K] @ W (Wt[256][KP] = W^T bf16, K zero-padded).
// Block = 128 rows x 256 cols, 8 waves (2 row-groups x 4 col-groups).
// Single-buffer LDS, 2 barriers/K-step. Epilogue: bf16 H store + per-wave
// 64-col dot partials -> LDS[row][wc] -> cross-wave sum -> ss/st directly.
template <bool A_FP32, int KSTEPS, int LDA, int KP>
__global__ __launch_bounds__(512, 4) void gemm_mfma(const void* __restrict__ Av,
                                                    const bf16_t* __restrict__ Wt,
                                                    bf16_t* __restrict__ H,
                                                    const float* __restrict__ avec,
                                                    float* __restrict__ ss_o,
                                                    float* __restrict__ st_o) {
    __shared__ bf16_t As[128][32];     // 8 KB
    __shared__ bf16_t Bs[256][32];     // 16 KB
    __shared__ float  red[2][128][4];  // 4 KB: [ss/st][row-in-block][wc]
    const int tid  = threadIdx.x;
    const int lane = tid & 63;
    const int w    = tid >> 6;       // wave 0..7
    const int wr   = w >> 2;         // row-group 0..1
    const int wc   = w & 3;          // col-group 0..3
    const int fr   = lane & 15;
    const int kg   = lane >> 4;      // k-group 0..3
    const int row0 = blockIdx.x * 128;

    const int sra  = tid >> 2;       // As staging row 0..127
    const int ska  = (tid & 3) * 8;  // As staging elem offset
    int sgrow = row0 + sra; if (sgrow >= N_ATOMS) sgrow = N_ATOMS - 1;

    f32x4 acc[4][4] = {};

    for (int ks = 0; ks < KSTEPS; ++ks) {
        const int k0 = ks * 32;
        if (ks) __syncthreads();

        if constexpr (A_FP32) {
            const float* A = (const float*)Av;
            short v[8];
            #pragma unroll
            for (int j = 0; j < 8; ++j) {
                int gk = k0 + ska + j;
                v[j] = (gk < LDA) ? (short)f2bf(A[(long long)sgrow * LDA + gk]) : (short)0;
            }
            *(bf16x8*)&As[sra][ska] = *(bf16x8*)v;
        } else {
            gload_lds16((const bf16_t*)Av + (long long)sgrow * LDA + k0 + ska,
                        (char*)&As[0][0] + w * 1024);
        }
        gload_lds16(Wt + (long long)(tid >> 2) * KP + k0 + ska,
                    (char*)&Bs[0][0] + w * 1024);
        gload_lds16(Wt + (long long)(128 + (tid >> 2)) * KP + k0 + ska,
                    (char*)&Bs[0][0] + 8192 + w * 1024);
        __syncthreads();

        const int koff = kg * 8;
        bf16x8 af[4], bfr[4];
        #pragma unroll
        for (int i = 0; i < 4; ++i)
            af[i] = *(const bf16x8*)&As[wr * 64 + i * 16 + fr][koff];
        #pragma unroll
        for (int jn = 0; jn < 4; ++jn)
            bfr[jn] = *(const bf16x8*)&Bs[wc * 64 + jn * 16 + fr][koff];
        #pragma unroll
        for (int i = 0; i < 4; ++i)
            #pragma unroll
            for (int jn = 0; jn < 4; ++jn)
                acc[i][jn] = __builtin_amdgcn_mfma_f32_16x16x32_bf16(af[i], bfr[jn], acc[i][jn], 0, 0, 0);
    }

    // ---- epilogue: H store + dot partials -> LDS -> final ss/st ----
    float as_v[4], at_v[4];
    #pragma unroll
    for (int jn = 0; jn < 4; ++jn) {
        int c = wc * 64 + jn * 16 + fr;
        as_v[jn] = avec[c];
        at_v[jn] = avec[HID + c];
    }
    #pragma unroll
    for (int i = 0; i < 4; ++i) {
        #pragma unroll
        for (int rr = 0; rr < 4; ++rr) {
            int row_l = wr * 64 + i * 16 + kg * 4 + rr;
            int r = row0 + row_l;
            float ps = 0.f, pt = 0.f;
            #pragma unroll
            for (int jn = 0; jn < 4; ++jn) {
                float h = acc[i][jn][rr];
                ps += h * as_v[jn];
                pt += h * at_v[jn];
                if (r < N_ATOMS)
                    H[(long long)r * HID + (wc * 64 + jn * 16 + fr)] = f2bf(h);
            }
            #pragma unroll
            for (int o = 1; o < 16; o <<= 1) {   // reduce across the 16 col-lanes
                ps += __shfl_xor(ps, o);
                pt += __shfl_xor(pt, o);
            }
            if (fr == 0) {
                red[0][row_l][wc] = ps;          // unique writer per (row_l, wc)
                red[1][row_l][wc] = pt;
            }
        }
    }
    __syncthreads();
    if (tid < 128) {
        int r = row0 + tid;
        if (r < N_ATOMS) {
            ss_o[r] = (red[0][tid][0] + red[0][tid][1]) + (red[0][tid][2] + red[0][tid][3]);
            st_o[r] = (red[1][tid][0] + red[1][tid][1]) + (red[1][tid][2] + red[1][tid][3]);
        }
    }
}

// ---------------- persistent fused softmax-aggregate + residual + ELU ----------------
// 8192 waves grid-stride over targets; next target's (cnt, lst, st, X-row)
// prefetched before processing the current one. Edge loads branch-skipped
// beyond n (n is wave-uniform) -- no wasted gather bandwidth.
__global__ __launch_bounds__(256) void aggregate(const bf16_t* __restrict__ H,
                                                 const float* __restrict__ ss,
                                                 const float* __restrict__ st,
                                                 const int* __restrict__ cnt,
                                                 const int* __restrict__ lst,
                                                 bf16_t* __restrict__ X,
                                                 int residual) {
    const int lane   = threadIdx.x & 63;
    const int nwaves = AGG_BLOCKS * 4;
    int t = (blockIdx.x * 256 + threadIdx.x) >> 6;   // 0..nwaves-1, all < N_ATOMS

    // current-target prefetch state
    int    n_c  = cnt[t];
    int4   a_c  = *(const int4*)&lst[t * CAP];
    float  st_c = st[t];
    float4 xv_c = make_float4(0.f, 0.f, 0.f, 0.f);
    if (residual) xv_c = ld4(&X[(size_t)(t * HID) + lane * 4]);

    for (;;) {
        // ---- prefetch next target (hides index/row latency under compute) ----
        const int t_n = t + nwaves;
        const bool more = (t_n < N_ATOMS);
        int n_x = 0; int4 a_x = make_int4(0, 0, 0, 0);
        float st_x = 0.f; float4 xv_x = make_float4(0.f, 0.f, 0.f, 0.f);
        if (more) {
            n_x  = cnt[t_n];
            a_x  = *(const int4*)&lst[t_n * CAP];
            st_x = st[t_n];
            if (residual) xv_x = ld4(&X[(size_t)(t_n * HID) + lane * 4]);
        }

        // ---- process current target ----
        const int n = n_c < CAP ? n_c : CAP;
        const float stt = st_c;
        const float4 z = make_float4(0.f, 0.f, 0.f, 0.f);

        float v0 = 0.f, v1 = 0.f, v2 = 0.f, v3 = 0.f;
        float4 h0 = z, h1 = z, h2 = z, h3 = z;
        if (n > 0) { v0 = ss[a_c.x]; h0 = ld4(&H[(size_t)(a_c.x * HID) + lane * 4]); }
        if (n > 1) { v1 = ss[a_c.y]; h1 = ld4(&H[(size_t)(a_c.y * HID) + lane * 4]); }
        if (n > 2) { v2 = ss[a_c.z]; h2 = ld4(&H[(size_t)(a_c.z * HID) + lane * 4]); }
        if (n > 3) { v3 = ss[a_c.w]; h3 = ld4(&H[(size_t)(a_c.w * HID) + lane * 4]); }

        float e0 = v0 + stt; e0 = e0 > 0.f ? e0 : 0.2f * e0;
        float e1 = v1 + stt; e1 = e1 > 0.f ? e1 : 0.2f * e1;
        float e2 = v2 + stt; e2 = e2 > 0.f ? e2 : 0.2f * e2;
        float e3 = v3 + stt; e3 = e3 > 0.f ? e3 : 0.2f * e3;
        float w0 = (n > 0) ? __expf(e0) : 0.f;
        float w1 = (n > 1) ? __expf(e1) : 0.f;
        float w2 = (n > 2) ? __expf(e2) : 0.f;
        float w3 = (n > 3) ? __expf(e3) : 0.f;

        float denom = (w0 + w1) + (w2 + w3);
        float ax = w0 * h0.x + w1 * h1.x + w2 * h2.x + w3 * h3.x;
        float ay = w0 * h0.y + w1 * h1.y + w2 * h2.y + w3 * h3.y;
        float az = w0 * h0.z + w1 * h1.z + w2 * h2.z + w3 * h3.z;
        float aw = w0 * h0.w + w1 * h1.w + w2 * h2.w + w3 * h3.w;

        // tail (n > 4): ~37% of targets, chunk-of-4
        for (int i0 = 4; i0 < n; i0 += 4) {
            int4 s4 = *(const int4*)&lst[t * CAP + i0];
            float vA = ss[s4.x];
            float4 hA = ld4(&H[(size_t)(s4.x * HID) + lane * 4]);
            float vB = 0.f, vC = 0.f, vD = 0.f;
            float4 hB = z, hC = z, hD = z;
            if (i0 + 1 < n) { vB = ss[s4.y]; hB = ld4(&H[(size_t)(s4.y * HID) + lane * 4]); }
            if (i0 + 2 < n) { vC = ss[s4.z]; hC = ld4(&H[(size_t)(s4.z * HID) + lane * 4]); }
            if (i0 + 3 < n) { vD = ss[s4.w]; hD = ld4(&H[(size_t)(s4.w * HID) + lane * 4]); }

            float eA = vA + stt; eA = eA > 0.f ? eA : 0.2f * eA;
            float eB = vB + stt; eB = eB > 0.f ? eB : 0.2f * eB;
            float eC = vC + stt; eC = eC > 0.f ? eC : 0.2f * eC;
            float eD = vD + stt; eD = eD > 0.f ? eD : 0.2f * eD;
            float wA = __expf(eA);
            float wB = (i0 + 1 < n) ? __expf(eB) : 0.f;
            float wC = (i0 + 2 < n) ? __expf(eC) : 0.f;
            float wD = (i0 + 3 < n) ? __expf(eD) : 0.f;

            denom += (wA + wB) + (wC + wD);
            ax += wA * hA.x + wB * hB.x + wC * hC.x + wD * hD.x;
            ay += wA * hA.y + wB * hB.y + wC * hC.y + wD * hD.y;
            az += wA * hA.z + wB * hB.z + wC * hC.z + wD * hD.z;
            aw += wA * hA.w + wB * hB.w + wC * hC.w + wD * hD.w;
        }

        float inv = 1.f / (denom + 1e-8f);
        float rx = ax * inv, ry = ay * inv, rz = az * inv, rw = aw * inv;
        if (residual) { rx += xv_c.x; ry += xv_c.y; rz += xv_c.z; rw += xv_c.w; }
        rx = rx > 0.f ? rx : (__expf(rx) - 1.f);   // elu(alpha=1)
        ry = ry > 0.f ? ry : (__expf(ry) - 1.f);
        rz = rz > 0.f ? rz : (__expf(rz) - 1.f);
        rw = rw > 0.f ? rw : (__expf(rw) - 1.f);
        st4(&X[(size_t)(t * HID) + lane * 4], make_float4(rx, ry, rz, rw));

        if (!more) break;
        t = t_n; n_c = n_x; a_c = a_x; st_c = st_x; xv_c = xv_x;
    }
}

// ---------------- molecule mean pool (mol_ids int32, sorted) ----------------
__device__ inline int lower_bound_i(const int* a, int n, int v) {
    int lo = 0, hi = n;
    while (lo < hi) { int mid = (lo + hi) >> 1; if (a[mid] < v) lo = mid + 1; else hi = mid; }
    return lo;
}

__global__ __launch_bounds__(64) void pool_kernel(const bf16_t* __restrict__ X,
                                                  const int* __restrict__ mol,
                                                  float* __restrict__ out) {
    int m = blockIdx.x;
    int lane = threadIdx.x;
    int lo = lower_bound_i(mol, N_ATOMS, m);
    int hi = lower_bound_i(mol, N_ATOMS, m + 1);
    float ax = 0.f, ay = 0.f, az = 0.f, aw = 0.f;
    for (int i = lo; i < hi; ++i) {
        float4 v = ld4(&X[(long long)i * HID + lane * 4]);
        ax += v.x; ay += v.y; az += v.z; aw += v.w;
    }
    float c = (float)(hi - lo);
    float4 r = make_float4(0.f, 0.f, 0.f, 0.f);
    if (c > 0.f) {
        float inv = 1.f / c;
        r = make_float4(ax * inv, ay * inv, az * inv, aw * inv);
    }
    *(float4*)&out[(long long)m * HID + lane * 4] = r;
}

extern "C" void kernel_launch(void* const* d_in, const int* in_sizes, int n_in,
                              void* d_out, int out_size, void* d_ws, size_t ws_size,
                              hipStream_t stream) {
    const float* f_atoms = (const float*)d_in[0];
    const int*   ei      = (const int*)d_in[1];
    const int*   mol     = (const int*)d_in[2];
    const float* W0      = (const float*)d_in[3];
    const float* a0      = (const float*)d_in[4];
    const float* W1      = (const float*)d_in[5];
    const float* a1      = (const float*)d_in[6];
    const float* W2      = (const float*)d_in[7];
    const float* a2      = (const float*)d_in[8];
    float* out = (float*)d_out;

    char* ws = (char*)d_ws;
    size_t off = 0;
    bf16_t* X  = (bf16_t*)(ws + off); off += (size_t)N_ATOMS * HID * 2;   // 102.4 MB
    bf16_t* Hb = (bf16_t*)(ws + off); off += (size_t)N_ATOMS * HID * 2;   // 102.4 MB
    float* ss  = (float*)(ws + off);  off += (size_t)N_ATOMS * 4;
    float* st  = (float*)(ws + off);  off += (size_t)N_ATOMS * 4;
    int* cnt   = (int*)(ws + off);    off += (size_t)N_ATOMS * 4;
    int* lst   = (int*)(ws + off);    off += (size_t)N_ATOMS * CAP * 4;   // 25.6 MB
    if (ws_size < off) return;

    // d_out scratch: transposed weights only (131 KB); pool overwrites all of d_out.
    bf16_t* Wt = (bf16_t*)d_out;

    hipMemsetAsync(cnt, 0, (size_t)N_ATOMS * 4, stream);
    build_adj<<<(N_EDGES + 255) / 256, 256, 0, stream>>>(ei, cnt, lst);

    const int gemm_blocks = (N_ATOMS + 127) / 128;   // 1563

    // ---- layer 0: A = f_atoms fp32, K=133 padded to 160 ----
    transpose_w<<<(HID * 160 + 255) / 256, 256, 0, stream>>>(W0, Wt, FDIM, 160);
    gemm_mfma<true, 5, FDIM, 160><<<gemm_blocks, 512, 0, stream>>>(f_atoms, Wt, Hb, a0, ss, st);
    aggregate<<<AGG_BLOCKS, 256, 0, stream>>>(Hb, ss, st, cnt, lst, X, 0);

    // ---- layer 1 ----
    transpose_w<<<(HID * HID + 255) / 256, 256, 0, stream>>>(W1, Wt, HID, HID);
    gemm_mfma<false, 8, HID, HID><<<gemm_blocks, 512, 0, stream>>>(X, Wt, Hb, a1, ss, st);
    aggregate<<<AGG_BLOCKS, 256, 0, stream>>>(Hb, ss, st, cnt, lst, X, 1);

    // ---- layer 2 ----
    transpose_w<<<(HID * HID + 255) / 256, 256, 0, stream>>>(W2, Wt, HID, HID);
    gemm_mfma<false, 8, HID, HID><<<gemm_blocks, 512, 0, stream>>>(X, Wt, Hb, a2, ss, st);
    aggregate<<<AGG_BLOCKS, 256, 0, stream>>>(Hb, ss, st, cnt, lst, X, 1);

    pool_kernel<<<NMOLS, 64, 0, stream>>>(X, mol, out);
}

// Round 11
// 582.309 us; speedup vs baseline: 1.3182x; 1.0331x over previous
//
#include <hip/hip_runtime.h>

#define N_ATOMS 200000
#define N_EDGES 800000
#define FDIM    133
#define HID     256
#define NMOLS   8000
#define CAP     32   // Poisson(4) in-degree; P(deg>=32) ~ 1e-20

typedef unsigned short bf16_t;
typedef __attribute__((ext_vector_type(4))) float f32x4;
typedef __attribute__((ext_vector_type(8))) short bf16x8;

__device__ inline float bf2f(bf16_t u) {
    union { unsigned int i; float f; } v; v.i = ((unsigned int)u) << 16; return v.f;
}
__device__ inline bf16_t f2bf(float f) {
    union { float f; unsigned int i; } v; v.f = f;
    return (bf16_t)((v.i + 0x7fffu + ((v.i >> 16) & 1u)) >> 16);   // RNE
}
__device__ inline float4 ld4(const bf16_t* p) {
    ushort4 u = *(const ushort4*)p;
    return make_float4(bf2f(u.x), bf2f(u.y), bf2f(u.z), bf2f(u.w));
}
__device__ inline void st4(bf16_t* p, float4 v) {
    ushort4 u; u.x = f2bf(v.x); u.y = f2bf(v.y); u.z = f2bf(v.z); u.w = f2bf(v.w);
    *(ushort4*)p = u;
}

// async global->LDS, 16B/lane; lds dest is wave-uniform base (+lane*16 implicit)
__device__ inline void gload_lds16(const void* g, void* l) {
    __builtin_amdgcn_global_load_lds((const __attribute__((address_space(1))) unsigned int*)g,
                                     (__attribute__((address_space(3))) unsigned int*)l,
                                     16, 0, 0);
}

// ---------------- adjacency build (edge_index arrives as int32) ----------------
__global__ __launch_bounds__(256) void build_adj(const int* __restrict__ ei,
                                                 int* __restrict__ cnt,
                                                 int* __restrict__ lst) {
    int e = blockIdx.x * 256 + threadIdx.x;
    if (e >= N_EDGES) return;
    int s = ei[e];
    int t = ei[N_EDGES + e];
    int p = atomicAdd(&cnt[t], 1);
    if (p < CAP) lst[t * CAP + p] = s;
}

// ---------------- weight transpose+convert: Wt[n][k] = bf16(W[k][n]), zero-pad k>=K ----------------
__global__ __launch_bounds__(256) void transpose_w(const float* __restrict__ W,
                                                   bf16_t* __restrict__ Wt,
                                                   int K, int Kpad) {
    int idx = blockIdx.x * 256 + threadIdx.x;
    if (idx >= HID * Kpad) return;
    int n = idx / Kpad, k = idx - n * Kpad;
    Wt[idx] = (k < K) ? f2bf(W[k * HID + n]) : (bf16_t)0;
}

// ---------------- 8-wave full-N MFMA GEMM, double-buffered, + fused dots ----------------
// H[M x 256] = A[M x K] @ W (Wt[256][KP] = W^T bf16, K zero-padded).
// Block = 128 rows x 256 cols, 8 waves (2 row-groups x 4 col-groups).
// Double-buffered LDS (52KB): ISSUE(k+1) -> MFMA(k) -> COMMIT -> barrier, so the
// vmcnt(0) drain at the barrier lands AFTER compute (prefetch hidden under MFMA).
// Occupancy is VGPR-capped at 2 blocks/CU either way -> dbuf LDS is free here.
// Epilogue: bf16 H store + per-wave 64-col dot partials -> LDS -> ss/st directly.
template <bool A_FP32, int KSTEPS, int LDA, int KP>
__global__ __launch_bounds__(512, 4) void gemm_mfma(const void* __restrict__ Av,
                                                    const bf16_t* __restrict__ Wt,
                                                    bf16_t* __restrict__ H,
                                                    const float* __restrict__ avec,
                                                    float* __restrict__ ss_o,
                                                    float* __restrict__ st_o) {
    __shared__ bf16_t As[2][128][32];   // 2 x 8 KB
    __shared__ bf16_t Bs[2][256][32];   // 2 x 16 KB
    __shared__ float  red[2][128][4];   // 4 KB: [ss/st][row-in-block][wc]
    const int tid  = threadIdx.x;
    const int lane = tid & 63;
    const int w    = tid >> 6;       // wave 0..7
    const int wr   = w >> 2;         // row-group 0..1
    const int wc   = w & 3;          // col-group 0..3
    const int fr   = lane & 15;
    const int kg   = lane >> 4;      // k-group 0..3
    const int row0 = blockIdx.x * 128;

    const int sra  = tid >> 2;       // staging row 0..127
    const int ska  = (tid & 3) * 8;  // staging elem offset
    int sgrow = row0 + sra; if (sgrow >= N_ATOMS) sgrow = N_ATOMS - 1;

    // fp32-A staging registers (layer 0)
    float sreg[8];

#define ISSUE(ks_, buf_) do {                                                          \
    const int k0_ = (ks_) * 32;                                                        \
    if constexpr (A_FP32) {                                                            \
        _Pragma("unroll")                                                              \
        for (int j = 0; j < 8; ++j) {                                                  \
            int gk = k0_ + ska + j;                                                    \
            sreg[j] = (gk < LDA) ? ((const float*)Av)[(long long)sgrow * LDA + gk] : 0.f; \
        }                                                                              \
    } else {                                                                           \
        gload_lds16((const bf16_t*)Av + (long long)sgrow * LDA + k0_ + ska,            \
                    (char*)&As[buf_][0][0] + w * 1024);                                \
    }                                                                                  \
    gload_lds16(Wt + (long long)(tid >> 2) * KP + k0_ + ska,                           \
                (char*)&Bs[buf_][0][0] + w * 1024);                                    \
    gload_lds16(Wt + (long long)(128 + (tid >> 2)) * KP + k0_ + ska,                   \
                (char*)&Bs[buf_][0][0] + 8192 + w * 1024);                             \
} while (0)

#define COMMIT(buf_) do {                                                              \
    if constexpr (A_FP32) {                                                            \
        short v_[8];                                                                   \
        _Pragma("unroll")                                                              \
        for (int j = 0; j < 8; ++j) v_[j] = (short)f2bf(sreg[j]);                      \
        *(bf16x8*)&As[buf_][sra][ska] = *(bf16x8*)&v_[0];                              \
    }                                                                                  \
} while (0)

    f32x4 acc[4][4] = {};

    // prologue: stage tile 0 into buf 0
    ISSUE(0, 0);
    COMMIT(0);
    __syncthreads();                    // drains vmcnt+lgkm: tile 0 resident

    int buf = 0;
    for (int ks = 0; ks < KSTEPS; ++ks) {
        if (ks + 1 < KSTEPS) ISSUE(ks + 1, buf ^ 1);   // prefetch flies during MFMA

        const int koff = kg * 8;
        bf16x8 af[4], bfr[4];
        #pragma unroll
        for (int i = 0; i < 4; ++i)
            af[i] = *(const bf16x8*)&As[buf][wr * 64 + i * 16 + fr][koff];
        #pragma unroll
        for (int jn = 0; jn < 4; ++jn)
            bfr[jn] = *(const bf16x8*)&Bs[buf][wc * 64 + jn * 16 + fr][koff];
        #pragma unroll
        for (int i = 0; i < 4; ++i)
            #pragma unroll
            for (int jn = 0; jn < 4; ++jn)
                acc[i][jn] = __builtin_amdgcn_mfma_f32_16x16x32_bf16(af[i], bfr[jn], acc[i][jn], 0, 0, 0);

        if (ks + 1 < KSTEPS) COMMIT(buf ^ 1);          // fp32 path reg->LDS after compute
        __syncthreads();                 // drain lands after compute; next buf ready
        buf ^= 1;
    }
#undef ISSUE
#undef COMMIT

    // ---- epilogue: H store + dot partials -> LDS -> final ss/st ----
    float as_v[4], at_v[4];
    #pragma unroll
    for (int jn = 0; jn < 4; ++jn) {
        int c = wc * 64 + jn * 16 + fr;
        as_v[jn] = avec[c];
        at_v[jn] = avec[HID + c];
    }
    #pragma unroll
    for (int i = 0; i < 4; ++i) {
        #pragma unroll
        for (int rr = 0; rr < 4; ++rr) {
            int row_l = wr * 64 + i * 16 + kg * 4 + rr;
            int r = row0 + row_l;
            float ps = 0.f, pt = 0.f;
            #pragma unroll
            for (int jn = 0; jn < 4; ++jn) {
                float h = acc[i][jn][rr];
                ps += h * as_v[jn];
                pt += h * at_v[jn];
                if (r < N_ATOMS)
                    H[(long long)r * HID + (wc * 64 + jn * 16 + fr)] = f2bf(h);
            }
            #pragma unroll
            for (int o = 1; o < 16; o <<= 1) {   // reduce across the 16 col-lanes
                ps += __shfl_xor(ps, o);
                pt += __shfl_xor(pt, o);
            }
            if (fr == 0) {
                red[0][row_l][wc] = ps;          // unique writer per (row_l, wc)
                red[1][row_l][wc] = pt;
            }
        }
    }
    __syncthreads();
    if (tid < 128) {
        int r = row0 + tid;
        if (r < N_ATOMS) {
            ss_o[r] = (red[0][tid][0] + red[0][tid][1]) + (red[0][tid][2] + red[0][tid][3]);
            st_o[r] = (red[1][tid][0] + red[1][tid][1]) + (red[1][tid][2] + red[1][tid][3]);
        }
    }
}

// ---------------- fused softmax-aggregate + residual + ELU (r9 one-shot form) ----------------
// One wave per target; edges in chunks of 4 -> 4 independent gathers in flight.
// lst rows are 128B-aligned (CAP=32 ints) so int4 loads are in-bounds; slots
// beyond n are poison and clamped to t (weight forced 0) for memory safety.
__global__ __launch_bounds__(256) void aggregate(const bf16_t* __restrict__ H,
                                                 const float* __restrict__ ss,
                                                 const float* __restrict__ st,
                                                 const int* __restrict__ cnt,
                                                 const int* __restrict__ lst,
                                                 bf16_t* __restrict__ X,
                                                 int residual) {
    int wave = threadIdx.x >> 6;
    int lane = threadIdx.x & 63;
    int t = blockIdx.x * 4 + wave;
    if (t >= N_ATOMS) return;
    int n = cnt[t]; if (n > CAP) n = CAP;
    float stt = st[t];
    const int base = t * CAP;

    float ax = 0.f, ay = 0.f, az = 0.f, aw = 0.f;
    float denom = 0.f;

    for (int i0 = 0; i0 < n; i0 += 4) {
        int4 s4 = *(const int4*)&lst[base + i0];
        int s0 = (i0 + 0 < n) ? s4.x : t;
        int s1 = (i0 + 1 < n) ? s4.y : t;
        int s2 = (i0 + 2 < n) ? s4.z : t;
        int s3 = (i0 + 3 < n) ? s4.w : t;

        float v0 = ss[s0], v1 = ss[s1], v2 = ss[s2], v3 = ss[s3];

        float e0 = v0 + stt; e0 = e0 > 0.f ? e0 : 0.2f * e0;
        float e1 = v1 + stt; e1 = e1 > 0.f ? e1 : 0.2f * e1;
        float e2 = v2 + stt; e2 = e2 > 0.f ? e2 : 0.2f * e2;
        float e3 = v3 + stt; e3 = e3 > 0.f ? e3 : 0.2f * e3;

        float t0 = (i0 + 0 < n) ? __expf(e0) : 0.f;
        float t1 = (i0 + 1 < n) ? __expf(e1) : 0.f;
        float t2 = (i0 + 2 < n) ? __expf(e2) : 0.f;
        float t3 = (i0 + 3 < n) ? __expf(e3) : 0.f;

        float4 h0 = ld4(&H[(long long)s0 * HID + lane * 4]);
        float4 h1 = ld4(&H[(long long)s1 * HID + lane * 4]);
        float4 h2 = ld4(&H[(long long)s2 * HID + lane * 4]);
        float4 h3 = ld4(&H[(long long)s3 * HID + lane * 4]);

        denom += (t0 + t1) + (t2 + t3);
        ax += t0 * h0.x + t1 * h1.x + t2 * h2.x + t3 * h3.x;
        ay += t0 * h0.y + t1 * h1.y + t2 * h2.y + t3 * h3.y;
        az += t0 * h0.z + t1 * h1.z + t2 * h2.z + t3 * h3.z;
        aw += t0 * h0.w + t1 * h1.w + t2 * h2.w + t3 * h3.w;
    }

    float inv = 1.f / (denom + 1e-8f);
    float rx = ax * inv, ry = ay * inv, rz = az * inv, rw = aw * inv;
    if (residual) {
        float4 xv = ld4(&X[(long long)t * HID + lane * 4]);
        rx += xv.x; ry += xv.y; rz += xv.z; rw += xv.w;
    }
    rx = rx > 0.f ? rx : (__expf(rx) - 1.f);   // elu(alpha=1)
    ry = ry > 0.f ? ry : (__expf(ry) - 1.f);
    rz = rz > 0.f ? rz : (__expf(rz) - 1.f);
    rw = rw > 0.f ? rw : (__expf(rw) - 1.f);
    st4(&X[(long long)t * HID + lane * 4], make_float4(rx, ry, rz, rw));
}

// ---------------- molecule mean pool (mol_ids int32, sorted) ----------------
__device__ inline int lower_bound_i(const int* a, int n, int v) {
    int lo = 0, hi = n;
    while (lo < hi) { int mid = (lo + hi) >> 1; if (a[mid] < v) lo = mid + 1; else hi = mid; }
    return lo;
}

__global__ __launch_bounds__(64) void pool_kernel(const bf16_t* __restrict__ X,
                                                  const int* __restrict__ mol,
                                                  float* __restrict__ out) {
    int m = blockIdx.x;
    int lane = threadIdx.x;
    int lo = lower_bound_i(mol, N_ATOMS, m);
    int hi = lower_bound_i(mol, N_ATOMS, m + 1);
    float ax = 0.f, ay = 0.f, az = 0.f, aw = 0.f;
    for (int i = lo; i < hi; ++i) {
        float4 v = ld4(&X[(long long)i * HID + lane * 4]);
        ax += v.x; ay += v.y; az += v.z; aw += v.w;
    }
    float c = (float)(hi - lo);
    float4 r = make_float4(0.f, 0.f, 0.f, 0.f);
    if (c > 0.f) {
        float inv = 1.f / c;
        r = make_float4(ax * inv, ay * inv, az * inv, aw * inv);
    }
    *(float4*)&out[(long long)m * HID + lane * 4] = r;
}

extern "C" void kernel_launch(void* const* d_in, const int* in_sizes, int n_in,
                              void* d_out, int out_size, void* d_ws, size_t ws_size,
                              hipStream_t stream) {
    const float* f_atoms = (const float*)d_in[0];
    const int*   ei      = (const int*)d_in[1];
    const int*   mol     = (const int*)d_in[2];
    const float* W0      = (const float*)d_in[3];
    const float* a0      = (const float*)d_in[4];
    const float* W1      = (const float*)d_in[5];
    const float* a1      = (const float*)d_in[6];
    const float* W2      = (const float*)d_in[7];
    const float* a2      = (const float*)d_in[8];
    float* out = (float*)d_out;

    char* ws = (char*)d_ws;
    size_t off = 0;
    bf16_t* X  = (bf16_t*)(ws + off); off += (size_t)N_ATOMS * HID * 2;   // 102.4 MB
    bf16_t* Hb = (bf16_t*)(ws + off); off += (size_t)N_ATOMS * HID * 2;   // 102.4 MB
    float* ss  = (float*)(ws + off);  off += (size_t)N_ATOMS * 4;
    float* st  = (float*)(ws + off);  off += (size_t)N_ATOMS * 4;
    int* cnt   = (int*)(ws + off);    off += (size_t)N_ATOMS * 4;
    int* lst   = (int*)(ws + off);    off += (size_t)N_ATOMS * CAP * 4;   // 25.6 MB
    if (ws_size < off) return;

    // d_out scratch: transposed weights only (131 KB); pool overwrites all of d_out.
    bf16_t* Wt = (bf16_t*)d_out;

    hipMemsetAsync(cnt, 0, (size_t)N_ATOMS * 4, stream);
    build_adj<<<(N_EDGES + 255) / 256, 256, 0, stream>>>(ei, cnt, lst);

    const int gemm_blocks = (N_ATOMS + 127) / 128;   // 1563
    const int agg_blocks  = N_ATOMS / 4;             // 50000

    // ---- layer 0: A = f_atoms fp32, K=133 padded to 160 ----
    transpose_w<<<(HID * 160 + 255) / 256, 256, 0, stream>>>(W0, Wt, FDIM, 160);
    gemm_mfma<true, 5, FDIM, 160><<<gemm_blocks, 512, 0, stream>>>(f_atoms, Wt, Hb, a0, ss, st);
    aggregate<<<agg_blocks, 256, 0, stream>>>(Hb, ss, st, cnt, lst, X, 0);

    // ---- layer 1 ----
    transpose_w<<<(HID * HID + 255) / 256, 256, 0, stream>>>(W1, Wt, HID, HID);
    gemm_mfma<false, 8, HID, HID><<<gemm_blocks, 512, 0, stream>>>(X, Wt, Hb, a1, ss, st);
    aggregate<<<agg_blocks, 256, 0, stream>>>(Hb, ss, st, cnt, lst, X, 1);

    // ---- layer 2 ----
    transpose_w<<<(HID * HID + 255) / 256, 256, 0, stream>>>(W2, Wt, HID, HID);
    gemm_mfma<false, 8, HID, HID><<<gemm_blocks, 512, 0, stream>>>(X, Wt, Hb, a2, ss, st);
    aggregate<<<agg_blocks, 256, 0, stream>>>(Hb, ss, st, cnt, lst, X, 1);

    pool_kernel<<<NMOLS, 64, 0, stream>>>(X, mol, out);
}